// Round 3
// baseline (9969.274 us; speedup 1.0000x reference)
//
#include <hip/hip_runtime.h>

// RNN: h_t = tanh(W_hh h_{t-1} + b_hh + W_xh emb[X_t] + b_xh)
// N=64, L=2048, V=32000, H=512.
//
// K1: Xh' = emb[X] @ W_xh^T + (b_xh + b_hh) -> written INTO d_out (fp16 MFMA, fp32 accum).
// K2: 4 WGs x 256 thr (4 waves, 1 wave/SIMD -> 512-reg budget/wave). WG g owns batch
//     rows [16g,16g+16) and ALL 512 cols; wave w owns cols [128w,128w+128).
//     W_hh per wave = 128 frags: 96 in VGPR/AGPR (384 regs), 32 in LDS (ks%4==0).
//     B-operand carries all 16 batch rows (full MFMA). h in single 16 KB LDS buffer,
//     16B-chunk XOR-swizzled; 2 barriers/step; no cross-WG communication; no spill
//     (fits 512-reg budget at 1 wave/EU).

typedef _Float16 half8 __attribute__((ext_vector_type(8)));
typedef float    f32x4 __attribute__((ext_vector_type(4)));

#define MFMA_F16(A,B,C) __builtin_amdgcn_mfma_f32_16x16x32_f16(A,B,C,0,0,0)

static __device__ __forceinline__ half8 cvt8(const float* p){
  const f32x4* q = (const f32x4*)p;
  f32x4 a = q[0], b = q[1];
  half8 r;
  r[0]=(_Float16)a[0]; r[1]=(_Float16)a[1]; r[2]=(_Float16)a[2]; r[3]=(_Float16)a[3];
  r[4]=(_Float16)b[0]; r[5]=(_Float16)b[1]; r[6]=(_Float16)b[2]; r[7]=(_Float16)b[3];
  return r;
}

static __device__ __forceinline__ float tanh_fast(float z){
  float e = __expf(2.0f*z);
  return 1.0f - 2.0f/(e + 1.0f);
}

// ---------------- Kernel 1: Xh' = E @ Wxh^T + (bxh + bhh) -> d_out ----------------
__global__ __launch_bounds__(256) void k_xh(
    const int* __restrict__ X, const float* __restrict__ emb,
    const float* __restrict__ Wxh, const float* __restrict__ bxh,
    const float* __restrict__ bhh, float* __restrict__ out)
{
  const int bid = blockIdx.x;
  const int bm = bid >> 3;
  const int bn = bid & 7;
  const int tid = threadIdx.x;
  const int w  = tid >> 6;
  const int l  = tid & 63;
  const int lr = l & 15, lq = l >> 4;

  const int mbase = bm*64 + (w>>1)*32;
  const int nbase = bn*64 + (w&1)*32;

  const int tok0 = X[mbase + lr];
  const int tok1 = X[mbase + 16 + lr];
  const int c0 = nbase + lr;
  const int c1 = nbase + 16 + lr;
  const float bs0 = bxh[c0] + bhh[c0];
  const float bs1 = bxh[c1] + bhh[c1];

  const float* a0 = emb + (long long)tok0*512 + lq*8;
  const float* a1 = emb + (long long)tok1*512 + lq*8;
  const float* b0 = Wxh + (long long)c0*512 + lq*8;
  const float* b1 = Wxh + (long long)c1*512 + lq*8;

  f32x4 acc00 = {0,0,0,0}, acc01 = {0,0,0,0}, acc10 = {0,0,0,0}, acc11 = {0,0,0,0};

  #pragma unroll
  for (int ks=0; ks<16; ++ks){
    half8 A0 = cvt8(a0 + ks*32);
    half8 A1 = cvt8(a1 + ks*32);
    half8 B0 = cvt8(b0 + ks*32);
    half8 B1 = cvt8(b1 + ks*32);
    acc00 = MFMA_F16(A0, B0, acc00);
    acc01 = MFMA_F16(A0, B1, acc01);
    acc10 = MFMA_F16(A1, B0, acc10);
    acc11 = MFMA_F16(A1, B1, acc11);
  }
  #pragma unroll
  for (int r=0; r<4; ++r){
    const long long m0 = mbase + 4*lq + r;
    const long long m1 = m0 + 16;
    out[m0*512 + c0] = acc00[r] + bs0;
    out[m0*512 + c1] = acc01[r] + bs1;
    out[m1*512 + c0] = acc10[r] + bs0;
    out[m1*512 + c1] = acc11[r] + bs1;
  }
}

// ---------------- Kernel 2: the recurrence ----------------
__global__ __launch_bounds__(256, 1) void k_rnn(
    const float* __restrict__ Whh,
    float* __restrict__ out)
{
  const int g   = blockIdx.x;          // batch group: rows [16g, 16g+16)
  const int tid = threadIdx.x;
  const int w   = tid >> 6;            // wave 0..3 owns cols [128w, 128w+128)
  const int l   = tid & 63;
  const int lr  = l & 15;              // A-row (h-out col) / B-col (batch) / D-col (batch)
  const int kg  = l >> 4;              // k-group
  const int r7  = lr & 7;
  const int colbase = w * 128;

  __shared__ _Float16 wlds[4][32][512];  // 128 KB: [wave][frag = ct*4 + ks/4][lane*8]
  __shared__ _Float16 hb[16][512];       // 16 KB: h, 16B-chunk XOR-swizzled per row

  // zero h0
  {
    f32x4 z = {0,0,0,0};
    f32x4* hz = (f32x4*)&hb[0][0];
    for (int i = tid; i < 16*512*2/16; i += 256) hz[i] = z;
  }

  // Load W_hh fragments. Frag (ct,ks): lane -> Whh[col = colbase+16ct+lr][k = 32ks+8kg+e].
  // ks%4==0 -> LDS (32 frags), else -> registers (96 frags = 384 VGPRs).
  half8 Wreg[8][12];
  #pragma unroll
  for (int ct = 0; ct < 8; ++ct){
    const float* wp = Whh + (long long)(colbase + ct*16 + lr)*512 + kg*8;
    #pragma unroll
    for (int ks = 0; ks < 16; ++ks){
      half8 v = cvt8(wp + ks*32);
      if ((ks & 3) == 0) *(half8*)&wlds[w][ct*4 + (ks>>2)][l*8] = v;
      else               Wreg[ct][ks - (ks>>2) - 1] = v;
    }
  }
  __syncthreads();

  const long long nbase = (long long)(g*16 + lr) * (2048LL*512);

  for (int t = 0; t < 2048; ++t){
    // prefetch xh' for this step (consumed in epilogue ~1300 cy later; hides HBM latency)
    const float* op = out + nbase + (long long)t*512 + colbase + kg*4;
    f32x4 xh[8];
    #pragma unroll
    for (int ct = 0; ct < 8; ++ct) xh[ct] = *(const f32x4*)(op + ct*16);

    f32x4 acc[8];
    #pragma unroll
    for (int ct = 0; ct < 8; ++ct) acc[ct] = (f32x4){0,0,0,0};

    // MFMA phase: B-frag = h[batch = lr][k = 32ks + 8kg + e], swizzled chunk (4ks+kg)^r7
    #pragma unroll
    for (int ks = 0; ks < 16; ++ks){
      half8 hf = *(const half8*)((const char*)&hb[lr][0] + (((4*ks + kg) ^ r7) << 4));
      if ((ks & 3) == 0){
        const int fs = ks >> 2;
        #pragma unroll
        for (int ct = 0; ct < 8; ++ct)
          acc[ct] = MFMA_F16(*(const half8*)&wlds[w][ct*4 + fs][l*8], hf, acc[ct]);
      } else {
        const int j = ks - (ks>>2) - 1;
        #pragma unroll
        for (int ct = 0; ct < 8; ++ct)
          acc[ct] = MFMA_F16(Wreg[ct][j], hf, acc[ct]);
      }
    }
    __syncthreads();   // all waves done reading h(t-1)

    // epilogue: lane holds D[i = 4kg+r][j = lr] per ct -> h col = colbase+16ct+4kg+r, batch lr
    #pragma unroll
    for (int ct = 0; ct < 8; ++ct){
      f32x4 hv;
      #pragma unroll
      for (int r = 0; r < 4; ++r) hv[r] = tanh_fast(acc[ct][r] + xh[ct][r]);
      *(f32x4*)(out + nbase + (long long)t*512 + colbase + ct*16 + kg*4) = hv;

      union { _Float16 h[4]; unsigned long long u; } pk;
      #pragma unroll
      for (int r = 0; r < 4; ++r) pk.h[r] = (_Float16)hv[r];
      const int byte = (colbase + ct*16 + kg*4) * 2;
      const int c0   = byte >> 4;          // 16B chunk index
      const int off8 = byte & 15;          // 0 or 8
      *(unsigned long long*)((char*)&hb[lr][0] + (((c0 ^ r7) << 4) + off8)) = pk.u;
    }
    __syncthreads();   // h(t) visible to all waves
  }
}

extern "C" void kernel_launch(void* const* d_in, const int* in_sizes, int n_in,
                              void* d_out, int out_size, void* d_ws, size_t ws_size,
                              hipStream_t stream)
{
  const int*   X    = (const int*)  d_in[0];
  const float* emb  = (const float*)d_in[1];
  const float* Whh  = (const float*)d_in[2];
  const float* bhh  = (const float*)d_in[3];
  const float* Wxh  = (const float*)d_in[4];
  const float* bxh  = (const float*)d_in[5];
  float* out = (float*)d_out;

  hipLaunchKernelGGL(k_xh,  dim3(16384), dim3(256), 0, stream, X, emb, Wxh, bxh, bhh, out);
  hipLaunchKernelGGL(k_rnn, dim3(4),     dim3(256), 0, stream, Whh, out);
}